// Round 15
// baseline (695.115 us; speedup 1.0000x reference)
//
#include <hip/hip_runtime.h>
#include <hip/hip_fp16.h>
#include <math.h>

// NODE_DIM=3, EMBED=16
#define ND 3
#define EM 16
#define BQ 512        // nodes per bucket (power of 2)
#define BQ_SH 9
#define MAXB 1024     // max buckets => supports N <= 524288
#define CHK 8192      // edges per edge_bin block (16 per thread @512)
#define COLS 12288    // LDS staging bound (mean bucket edges ~8192, +45 sigma)
// packed pair: (dst & 511) << 23 | src
#define P_SH 23
#define PMASK ((1u << P_SH) - 1)
// packed cw: (wq << 19) | src  (src < 2^19 since N <= 524288;
// wq = round(w * 256), 13 bits, saturating -> w in [0, 32), res 1/256)
#define CW_SH 19
#define CW_SRCM ((1u << CW_SH) - 1)
#define WSCALE 256.0f
#define WINV (1.0f / 256.0f)

#define NTL(p) __builtin_nontemporal_load(p)

__device__ __forceinline__ float sp(float x) {
    // jax.nn.softplus = max(x,0) + log1p(exp(-|x|))
    return fmaxf(x, 0.0f) + log1pf(expf(-fabsf(x)));
}

__device__ __forceinline__ void nt_store_h2(__half2 v, __half2* p) {
    // nontemporal builtin rejects __half2*; bit-cast to u32 (same 4B store)
    union { __half2 h; unsigned int u; } cv;
    cv.h = v;
    __builtin_nontemporal_store(cv.u, (unsigned int*)p);
}

// Kernel 0: zero bucket counters.
__global__ __launch_bounds__(1024) void bucket_zero(int* __restrict__ bcnt)
{
    bcnt[threadIdx.x] = 0;
}

// Kernel 0b: repack pos into float4 (one dwordx4 gather in csr_init).
__global__ __launch_bounds__(256) void pos4_pack(
    const float* __restrict__ pos, float4* __restrict__ pos4, int N)
{
    int n = blockIdx.x * 256 + threadIdx.x;
    if (n >= N) return;
    pos4[n] = make_float4(pos[3 * (size_t)n + 0], pos[3 * (size_t)n + 1],
                          pos[3 * (size_t)n + 2], 0.0f);
}

// Kernel A: bucket histogram of dst (bucket = dst >> 9).
__global__ __launch_bounds__(256) void bucket_count(
    const int* __restrict__ ei, int* __restrict__ bcnt, int E, int NB)
{
    __shared__ int h[MAXB];
    int t = threadIdx.x;
    for (int i = t; i < MAXB; i += 256) h[i] = 0;
    __syncthreads();
    const int* dp = ei + (size_t)E;
    for (int e = blockIdx.x * 256 + t; e < E; e += gridDim.x * 256)
        atomicAdd(&h[((unsigned)dp[e]) >> BQ_SH], 1);
    __syncthreads();
    for (int i = t; i < NB; i += 256) {
        int v = h[i];
        if (v) atomicAdd(&bcnt[i], v);
    }
}

// Kernel B: exclusive scan of bucket counts (NB <= 1024) -> gbase, gcur.
__global__ __launch_bounds__(1024) void bucket_scan(
    const int* __restrict__ bcnt, int* __restrict__ gbase,
    int* __restrict__ gcur, int NB)
{
    __shared__ int sd[1024];
    int t = threadIdx.x;
    int v = (t < NB) ? bcnt[t] : 0;
    sd[t] = v;
    __syncthreads();
    for (int off = 1; off < 1024; off <<= 1) {
        int add = (t >= off) ? sd[t - off] : 0;
        __syncthreads();
        sd[t] += add;
        __syncthreads();
    }
    if (t < NB) { int ex = sd[t] - v; gbase[t] = ex; gcur[t] = ex; }
}

// Kernel C (512 threads): bin edges into bucket-contiguous packed-pair runs,
// LDS-sorted per chunk so global writes are in-order & coalesced.
__global__ __launch_bounds__(512) void edge_bin(
    const int* __restrict__ ei, int* __restrict__ gcur,
    unsigned int* __restrict__ pairs, int E)
{
    __shared__ int lcnt[MAXB];
    __shared__ int lbase[MAXB];
    __shared__ int sbase[MAXB];
    __shared__ unsigned int stage[CHK];
    __shared__ unsigned short bid[CHK];
    __shared__ int sd[512];
    int t = threadIdx.x;
    int c0 = blockIdx.x * CHK;
    int cntT = min(CHK, E - c0);
    for (int i = t; i < MAXB; i += 512) lcnt[i] = 0;
    __syncthreads();
    const int* dp = ei + (size_t)E;
    int dreg[16];
#pragma unroll
    for (int it = 0; it < 16; it++) {
        int e = c0 + it * 512 + t;
        dreg[it] = (e < E) ? dp[e] : 0;
        if (e < E) atomicAdd(&lcnt[((unsigned)dreg[it]) >> BQ_SH], 1);
    }
    __syncthreads();
    // exclusive scan of lcnt[1024] (2 per thread) -> lbase; reserve runs.
    int b2 = t * 2;
    int h0 = lcnt[b2], h1 = lcnt[b2 + 1];
    int s2 = h0 + h1;
    sd[t] = s2;
    __syncthreads();
    for (int off = 1; off < 512; off <<= 1) {
        int add = (t >= off) ? sd[t - off] : 0;
        __syncthreads();
        sd[t] += add;
        __syncthreads();
    }
    int ex = sd[t] - s2;
    lbase[b2]     = ex;
    lbase[b2 + 1] = ex + h0;
    sbase[b2]     = h0 ? atomicAdd(&gcur[b2], h0)     : 0;
    sbase[b2 + 1] = h1 ? atomicAdd(&gcur[b2 + 1], h1) : 0;
    lcnt[b2] = 0; lcnt[b2 + 1] = 0;
    __syncthreads();
#pragma unroll
    for (int it = 0; it < 16; it++) {
        int e = c0 + it * 512 + t;
        if (e < E) {
            int d = dreg[it];
            unsigned b = ((unsigned)d) >> BQ_SH;
            int s = ei[e];
            int pos = lbase[b] + atomicAdd(&lcnt[b], 1);
            stage[pos] = ((unsigned)(d & (BQ - 1)) << P_SH) | (unsigned)s;
            bid[pos] = (unsigned short)b;
        }
    }
    __syncthreads();
    for (int i = t; i < cntT; i += 512) {
        unsigned b = bid[i];
        pairs[sbase[b] + (i - lbase[b])] = stage[i];
    }
}

// Kernel D (512 threads, fused, WITH restage): per-bucket CSR build + edge
// weights + dinv + node_init. LDS stg restage -> cw written fully coalesced
// in index order. cw is packed u32 {wq:13 | src:19} (halves cw traffic for
// this kernel's write and both conv layers' reads).
__global__ __launch_bounds__(512) void bucket_csr_init(
    const unsigned int* __restrict__ pairs, const int* __restrict__ gbase,
    const int* __restrict__ bcnt, const float4* __restrict__ pos4,
    const float* __restrict__ W_init, const float* __restrict__ b_init,
    const float* __restrict__ W_g1,
    int* __restrict__ rowptr, unsigned int* __restrict__ cw,
    float* __restrict__ dinv, __half2* __restrict__ zh1, int N, int NB)
{
    __shared__ int ncnt[BQ];
    __shared__ int ncur[BQ];
    __shared__ float wsum[BQ];
    __shared__ int sd[512];
    __shared__ unsigned int stg[COLS];
    __shared__ float4 posS[BQ];
    __shared__ float sWi[ND * EM];
    __shared__ float sbi[EM];
    __shared__ float sW1[EM * EM];
    __shared__ float lx[64][EM + 2];
    int b = blockIdx.x;
    int t = threadIdx.x;
    int lo = b << BQ_SH;
    int hi = min(lo + BQ, N);
    int nloc = hi - lo;
    int r0 = gbase[b];
    int cntE = bcnt[b];
    if (t < ND * EM)  sWi[t] = W_init[t];
    if (t < EM)       sbi[t] = b_init[t];
    if (t < EM * EM)  sW1[t] = W_g1[t];
    if (t < nloc) posS[t] = pos4[lo + t];
    ncnt[t] = 0;
    wsum[t] = 0.0f;
    __syncthreads();
    for (int i = t; i < cntE; i += 512)
        atomicAdd(&ncnt[pairs[r0 + i] >> P_SH], 1);
    __syncthreads();
    // exclusive scan over 512 (1 per thread)
    int v = ncnt[t];
    sd[t] = v;
    __syncthreads();
    for (int off = 1; off < 512; off <<= 1) {
        int add = (t >= off) ? sd[t - off] : 0;
        __syncthreads();
        sd[t] += add;
        __syncthreads();
    }
    int ex = sd[t] - v;
    ncur[t] = ex;
    if (lo + t < hi) rowptr[lo + t] = r0 + ex;
    if (b == NB - 1 && t == 0) rowptr[N] = r0 + cntE;  // == E
    __syncthreads();
    bool fit = (cntE <= COLS);
    if (fit) {
        for (int i = t; i < cntE; i += 512) {
            unsigned p = pairs[r0 + i];
            int slot = atomicAdd(&ncur[p >> P_SH], 1);
            stg[slot] = p;
        }
        __syncthreads();
        for (int i = t; i < cntE; i += 512) {
            unsigned p = stg[i];
            int ldst = (int)(p >> P_SH);
            int src = (int)(p & PMASK);
            float4 pd = posS[ldst];
            float4 ps = pos4[src];
            float dx = pd.x - ps.x;
            float dy = pd.y - ps.y;
            float dz = pd.z - ps.z;
            float d = sqrtf(fmaf(dx, dx, fmaf(dy, dy, dz * dz)));
            unsigned wq = (unsigned)fminf(fmaf(d, WSCALE, 0.5f), 8191.0f);
            cw[r0 + i] = (unsigned)src | (wq << CW_SH);
            atomicAdd(&wsum[ldst], d);
        }
    } else {
        // overflow fallback (practically unreachable)
        for (int i = t; i < cntE; i += 512) {
            unsigned p = pairs[r0 + i];
            int ldst = (int)(p >> P_SH);
            int src = (int)(p & PMASK);
            int slot = atomicAdd(&ncur[ldst], 1);
            float4 pd = posS[ldst];
            float4 ps = pos4[src];
            float dx = pd.x - ps.x;
            float dy = pd.y - ps.y;
            float dz = pd.z - ps.z;
            float d = sqrtf(fmaf(dx, dx, fmaf(dy, dy, dz * dz)));
            unsigned wq = (unsigned)fminf(fmaf(d, WSCALE, 0.5f), 8191.0f);
            cw[r0 + slot] = (unsigned)src | (wq << CW_SH);
            atomicAdd(&wsum[ldst], d);
        }
    }
    __syncthreads();
    // epilogue: dinv + fused node_init -> zh1, 8-lane groups (low VGPR).
    int g = t >> 3, c = t & 7;          // 64 groups x 8 lanes
    for (int j = 0; j < BQ / 64; j++) {
        int nl = j * 64 + g;
        if (nl < nloc) {
            float4 pv = posS[nl];
            int k0 = 2 * c, k1 = 2 * c + 1;
            float h0 = fmaf(pv.x, sWi[0 * EM + k0],
                       fmaf(pv.y, sWi[1 * EM + k0],
                       fmaf(pv.z, sWi[2 * EM + k0], sbi[k0])));
            float h1 = fmaf(pv.x, sWi[0 * EM + k1],
                       fmaf(pv.y, sWi[1 * EM + k1],
                       fmaf(pv.z, sWi[2 * EM + k1], sbi[k1])));
            lx[g][k0] = sp(h0);
            lx[g][k1] = sp(h1);
            float di = rsqrtf(1.0f + wsum[nl]);
            int n = lo + nl;
            if (c == 0) dinv[n] = di;
            float ax = 0.0f, ay = 0.0f;
#pragma unroll
            for (int jj = 0; jj < EM; jj++) {
                float lj = lx[g][jj];
                ax = fmaf(lj, sW1[jj * EM + k0], ax);
                ay = fmaf(lj, sW1[jj * EM + k1], ay);
            }
            zh1[(size_t)n * 8 + c] =
                __float22half2_rn(make_float2(ax * di, ay * di));
        }
    }
}

// Kernel 6 (x2): fused GCN-mean layer on fp16 pre-scaled operand
// zh[s][c] = fp16(dinv[s]*x[s][c]). 8 lanes/node (lane = channel pair).
// Per edge per lane: one nt u32 cw load (decode src/wq) + one half2 z load;
// f32 accumulate. cw is nt so the read-once stream doesn't evict the z
// table from L2 (z-line fills were 92% miss with cw cached).
// mode 1: zout = fp16((x@W)*di)  (pre-scaled layer-2 operand).
// mode 2: fused head: y = sp(x@P1+b1); out = (y@P2+b2)/sig.
__global__ __launch_bounds__(256) void gather_conv(
    const int* __restrict__ rowptr, const unsigned int* __restrict__ cw,
    const float* __restrict__ dinv, const __half2* __restrict__ zin,
    const float* __restrict__ bconv, const float* __restrict__ W,
    const float* __restrict__ P1, const float* __restrict__ b1,
    const float* __restrict__ P2, const float* __restrict__ b2,
    const float* __restrict__ sig,
    __half2* __restrict__ zout, float* __restrict__ out, int N, int mode)
{
    __shared__ float sW[EM * EM];
    __shared__ float sP2[EM * ND];
    __shared__ float sb1[EM];
    __shared__ float sb2[ND];
    __shared__ float lx[32][EM + 1];
    int t = threadIdx.x;
    if (mode == 1) {
        sW[t] = W[t];
    } else {
        sW[t] = P1[t];
        if (t < EM)      sb1[t] = b1[t];
        if (t < EM * ND) sP2[t] = P2[t];
        if (t < ND)      sb2[t] = b2[t];
    }
    int g = t >> 3, c = t & 7;          // 32 node groups, 8 lanes each
    int n = blockIdx.x * 32 + g;

    float xx = 0.0f, xy = 0.0f;
    float di = 1.0f;
    if (n < N) {
        int start = rowptr[n], end = rowptr[n + 1];
        di = dinv[n];
        float2 zv = __half22float2(zin[(size_t)n * 8 + c]);  // self loop
        float a0x = zv.x, a0y = zv.y;
        float a1x = 0.f, a1y = 0.f, a2x = 0.f, a2y = 0.f, a3x = 0.f, a3y = 0.f;
        int j = start;
        for (; j + 3 < end; j += 4) {
            unsigned p0 = NTL(&cw[j]),     p1 = NTL(&cw[j + 1]);
            unsigned p2 = NTL(&cw[j + 2]), p3 = NTL(&cw[j + 3]);
            float2 z0 = __half22float2(zin[(size_t)(p0 & CW_SRCM) * 8 + c]);
            float2 z1 = __half22float2(zin[(size_t)(p1 & CW_SRCM) * 8 + c]);
            float2 z2 = __half22float2(zin[(size_t)(p2 & CW_SRCM) * 8 + c]);
            float2 z3 = __half22float2(zin[(size_t)(p3 & CW_SRCM) * 8 + c]);
            float w0 = (float)(p0 >> CW_SH) * WINV;
            float w1 = (float)(p1 >> CW_SH) * WINV;
            float w2 = (float)(p2 >> CW_SH) * WINV;
            float w3 = (float)(p3 >> CW_SH) * WINV;
            a0x = fmaf(w0, z0.x, a0x); a0y = fmaf(w0, z0.y, a0y);
            a1x = fmaf(w1, z1.x, a1x); a1y = fmaf(w1, z1.y, a1y);
            a2x = fmaf(w2, z2.x, a2x); a2y = fmaf(w2, z2.y, a2y);
            a3x = fmaf(w3, z3.x, a3x); a3y = fmaf(w3, z3.y, a3y);
        }
        for (; j < end; j++) {
            unsigned p = NTL(&cw[j]);
            float2 zr = __half22float2(zin[(size_t)(p & CW_SRCM) * 8 + c]);
            float wv = (float)(p >> CW_SH) * WINV;
            a0x = fmaf(wv, zr.x, a0x); a0y = fmaf(wv, zr.y, a0y);
        }
        float accx = (a0x + a1x) + (a2x + a3x);
        float accy = (a0y + a1y) + (a2y + a3y);
        float rc = 1.0f / (float)(end - start + 1);
        xx = sp(fmaf(accx * di, rc, bconv[2 * c]));
        xy = sp(fmaf(accy * di, rc, bconv[2 * c + 1]));
    }
    __syncthreads();      // sW/lx ready
    lx[g][2 * c]     = xx;
    lx[g][2 * c + 1] = xy;
    __syncthreads();
    if (n < N) {
        if (mode == 1) {
            float ax = 0.0f, ay = 0.0f;
#pragma unroll
            for (int j = 0; j < EM; j++) {
                float lj = lx[g][j];
                ax = fmaf(lj, sW[j * EM + 2 * c], ax);
                ay = fmaf(lj, sW[j * EM + 2 * c + 1], ay);
            }
            nt_store_h2(__float22half2_rn(make_float2(ax * di, ay * di)),
                        &zout[(size_t)n * 8 + c]);
        } else {
            // fused head: y = sp(x@P1+b1) over own row (wave-lockstep safe),
            // then out = (y@P2+b2)/sig.
            float ax = sb1[2 * c], ay = sb1[2 * c + 1];
#pragma unroll
            for (int j = 0; j < EM; j++) {
                float lj = lx[g][j];
                ax = fmaf(lj, sW[j * EM + 2 * c], ax);
                ay = fmaf(lj, sW[j * EM + 2 * c + 1], ay);
            }
            lx[g][2 * c]     = sp(ax);
            lx[g][2 * c + 1] = sp(ay);
            if (c < ND) {
                float o = sb2[c];
#pragma unroll
                for (int j = 0; j < EM; j++)
                    o = fmaf(lx[g][j], sP2[j * ND + c], o);
                __builtin_nontemporal_store(o / sig[n],
                                            &out[(size_t)n * ND + c]);
            }
        }
    }
}

extern "C" void kernel_launch(void* const* d_in, const int* in_sizes, int n_in,
                              void* d_out, int out_size, void* d_ws, size_t ws_size,
                              hipStream_t stream) {
    const float* pos    = (const float*)d_in[0];
    const float* sig    = (const float*)d_in[1];
    const int*   ei     = (const int*)d_in[2];
    const float* W_init = (const float*)d_in[4];
    const float* b_init = (const float*)d_in[5];
    const float* W_g1   = (const float*)d_in[6];
    const float* b_g1   = (const float*)d_in[7];
    const float* W_g2   = (const float*)d_in[8];
    const float* b_g2   = (const float*)d_in[9];
    const float* W_p1   = (const float*)d_in[10];
    const float* b_p1   = (const float*)d_in[11];
    const float* W_p2   = (const float*)d_in[12];
    const float* b_p2   = (const float*)d_in[13];
    float* out = (float*)d_out;

    int N = in_sizes[0] / ND;
    int E = in_sizes[2] / 2;
    size_t Ns = (size_t)N, Es = (size_t)E;
    int NB = (N + BQ - 1) >> BQ_SH;   // <= MAXB for N <= 524288

    // Workspace layout (4B elements):
    // rowptr[N+1] | bcnt[1024] | gbase[1024] | gcur[1024] | dinv[N]
    //   | (pad 16B) pos4[N] (float4) | cw[E] (u32) | pairs[E] (u32)
    //   | zh1[8N] (half2)
    // zh2 (8N half2 = 16MB) aliases pairs (32MB, dead after bucket_csr_init).
    int* rowptr = (int*)d_ws;
    int* bcnt   = rowptr + (Ns + 1);
    int* gbase  = bcnt + 1024;
    int* gcur   = gbase + 1024;
    float* dinv = (float*)(gcur + 1024);
    size_t off = (Ns + 1) + 3 * 1024 + Ns;
    off = (off + 3) & ~(size_t)3;           // 16B align for float4
    float4* pos4 = (float4*)((float*)d_ws + off);
    unsigned int* cw = (unsigned int*)(pos4 + Ns);
    unsigned int* pairs = cw + Es;
    __half2* zh2 = (__half2*)pairs;
    __half2* zh1 = (__half2*)(pairs + Es);

    int nbN = (N + 255) / 256;
    int nbG2 = (N + 31) / 32;           // gather_conv: 32 nodes/block
    int nbBin = (E + CHK - 1) / CHK;

    bucket_zero<<<1, 1024, 0, stream>>>(bcnt);
    pos4_pack<<<nbN, 256, 0, stream>>>(pos, pos4, N);
    bucket_count<<<1024, 256, 0, stream>>>(ei, bcnt, E, NB);
    bucket_scan<<<1, 1024, 0, stream>>>(bcnt, gbase, gcur, NB);
    edge_bin<<<nbBin, 512, 0, stream>>>(ei, gcur, pairs, E);
    bucket_csr_init<<<NB, 512, 0, stream>>>(pairs, gbase, bcnt, pos4,
        W_init, b_init, W_g1, rowptr, cw, dinv, zh1, N, NB);
    gather_conv<<<nbG2, 256, 0, stream>>>(rowptr, cw, dinv, zh1, b_g1, W_g2,
        W_p1, b_p1, W_p2, b_p2, sig, zh2, out, N, 1);
    gather_conv<<<nbG2, 256, 0, stream>>>(rowptr, cw, dinv, zh2, b_g2, W_g2,
        W_p1, b_p1, W_p2, b_p2, sig, zh2, out, N, 2);
}

// Round 16
// 651.110 us; speedup vs baseline: 1.0676x; 1.0676x over previous
//
#include <hip/hip_runtime.h>
#include <hip/hip_fp16.h>
#include <math.h>

// NODE_DIM=3, EMBED=16
#define ND 3
#define EM 16
#define BQ 512        // nodes per bucket (power of 2)
#define BQ_SH 9
#define MAXB 1024     // max buckets => supports N <= 524288
#define CHK 8192      // edges per edge_bin block (16 per thread @512)
#define COLS 12288    // LDS staging bound (mean bucket edges ~8192, +45 sigma)
// packed pair: (dst & 511) << 23 | src
#define P_SH 23
#define PMASK ((1u << P_SH) - 1)
// packed cw: (wq << 19) | src  (src < 2^19 since N <= 524288;
// wq = round(w * 256), 13 bits, saturating -> w in [0, 32), res 1/256)
#define CW_SH 19
#define CW_SRCM ((1u << CW_SH) - 1)
#define WSCALE 256.0f
#define WINV (1.0f / 256.0f)

__device__ __forceinline__ float sp(float x) {
    // jax.nn.softplus = max(x,0) + log1p(exp(-|x|))
    return fmaxf(x, 0.0f) + log1pf(expf(-fabsf(x)));
}

// Kernel 0: zero bucket counters.
__global__ __launch_bounds__(1024) void bucket_zero(int* __restrict__ bcnt)
{
    bcnt[threadIdx.x] = 0;
}

// Kernel A: bucket histogram of dst (bucket = dst >> 9).
__global__ __launch_bounds__(256) void bucket_count(
    const int* __restrict__ ei, int* __restrict__ bcnt, int E, int NB)
{
    __shared__ int h[MAXB];
    int t = threadIdx.x;
    for (int i = t; i < MAXB; i += 256) h[i] = 0;
    __syncthreads();
    const int* dp = ei + (size_t)E;
    for (int e = blockIdx.x * 256 + t; e < E; e += gridDim.x * 256)
        atomicAdd(&h[((unsigned)dp[e]) >> BQ_SH], 1);
    __syncthreads();
    for (int i = t; i < NB; i += 256) {
        int v = h[i];
        if (v) atomicAdd(&bcnt[i], v);
    }
}

// Kernel B: exclusive scan of bucket counts (NB <= 1024) -> gbase, gcur.
__global__ __launch_bounds__(1024) void bucket_scan(
    const int* __restrict__ bcnt, int* __restrict__ gbase,
    int* __restrict__ gcur, int NB)
{
    __shared__ int sd[1024];
    int t = threadIdx.x;
    int v = (t < NB) ? bcnt[t] : 0;
    sd[t] = v;
    __syncthreads();
    for (int off = 1; off < 1024; off <<= 1) {
        int add = (t >= off) ? sd[t - off] : 0;
        __syncthreads();
        sd[t] += add;
        __syncthreads();
    }
    if (t < NB) { int ex = sd[t] - v; gbase[t] = ex; gcur[t] = ex; }
}

// Kernel C (512 threads): bin edges into bucket-contiguous packed-pair runs,
// LDS-sorted per chunk so global writes are in-order & coalesced.
// (r10-proven configuration.)
__global__ __launch_bounds__(512) void edge_bin(
    const int* __restrict__ ei, int* __restrict__ gcur,
    unsigned int* __restrict__ pairs, int E)
{
    __shared__ int lcnt[MAXB];
    __shared__ int lbase[MAXB];
    __shared__ int sbase[MAXB];
    __shared__ unsigned int stage[CHK];
    __shared__ unsigned short bid[CHK];
    __shared__ int sd[512];
    int t = threadIdx.x;
    int c0 = blockIdx.x * CHK;
    int cntT = min(CHK, E - c0);
    for (int i = t; i < MAXB; i += 512) lcnt[i] = 0;
    __syncthreads();
    const int* dp = ei + (size_t)E;
    int dreg[16];
#pragma unroll
    for (int it = 0; it < 16; it++) {
        int e = c0 + it * 512 + t;
        dreg[it] = (e < E) ? dp[e] : 0;
        if (e < E) atomicAdd(&lcnt[((unsigned)dreg[it]) >> BQ_SH], 1);
    }
    __syncthreads();
    // exclusive scan of lcnt[1024] (2 per thread) -> lbase; reserve runs.
    int b2 = t * 2;
    int h0 = lcnt[b2], h1 = lcnt[b2 + 1];
    int s2 = h0 + h1;
    sd[t] = s2;
    __syncthreads();
    for (int off = 1; off < 512; off <<= 1) {
        int add = (t >= off) ? sd[t - off] : 0;
        __syncthreads();
        sd[t] += add;
        __syncthreads();
    }
    int ex = sd[t] - s2;
    lbase[b2]     = ex;
    lbase[b2 + 1] = ex + h0;
    sbase[b2]     = h0 ? atomicAdd(&gcur[b2], h0)     : 0;
    sbase[b2 + 1] = h1 ? atomicAdd(&gcur[b2 + 1], h1) : 0;
    lcnt[b2] = 0; lcnt[b2 + 1] = 0;
    __syncthreads();
#pragma unroll
    for (int it = 0; it < 16; it++) {
        int e = c0 + it * 512 + t;
        if (e < E) {
            int d = dreg[it];
            unsigned b = ((unsigned)d) >> BQ_SH;
            int s = ei[e];
            int pos = lbase[b] + atomicAdd(&lcnt[b], 1);
            stage[pos] = ((unsigned)(d & (BQ - 1)) << P_SH) | (unsigned)s;
            bid[pos] = (unsigned short)b;
        }
    }
    __syncthreads();
    for (int i = t; i < cntT; i += 512) {
        unsigned b = bid[i];
        pairs[sbase[b] + (i - lbase[b])] = stage[i];
    }
}

// Kernel D (512 threads, fused, WITH restage): per-bucket CSR build + edge
// weights + dinv + node_init. LDS stg restage -> cw written fully coalesced
// in index order. cw is packed u32 {wq:13 | src:19} (halves this kernel's
// cw write and both conv layers' cw reads). r10-proven shape otherwise.
__global__ __launch_bounds__(512) void bucket_csr_init(
    const unsigned int* __restrict__ pairs, const int* __restrict__ gbase,
    const int* __restrict__ bcnt, const float* __restrict__ pos,
    const float* __restrict__ W_init, const float* __restrict__ b_init,
    const float* __restrict__ W_g1,
    int* __restrict__ rowptr, unsigned int* __restrict__ cw,
    float* __restrict__ dinv, __half2* __restrict__ zh1, int N, int NB)
{
    __shared__ int ncnt[BQ];
    __shared__ int ncur[BQ];
    __shared__ float wsum[BQ];
    __shared__ int sd[512];
    __shared__ unsigned int stg[COLS];
    __shared__ float posS[BQ * 3];
    __shared__ float sWi[ND * EM];
    __shared__ float sbi[EM];
    __shared__ float sW1[EM * EM];
    __shared__ float lx[64][EM + 2];
    int b = blockIdx.x;
    int t = threadIdx.x;
    int lo = b << BQ_SH;
    int hi = min(lo + BQ, N);
    int nloc = hi - lo;
    int r0 = gbase[b];
    int cntE = bcnt[b];
    if (t < ND * EM)  sWi[t] = W_init[t];
    if (t < EM)       sbi[t] = b_init[t];
    if (t < EM * EM)  sW1[t] = W_g1[t];
    for (int i = t; i < 3 * nloc; i += 512) posS[i] = pos[(size_t)lo * 3 + i];
    ncnt[t] = 0;
    wsum[t] = 0.0f;
    __syncthreads();
    for (int i = t; i < cntE; i += 512)
        atomicAdd(&ncnt[pairs[r0 + i] >> P_SH], 1);
    __syncthreads();
    // exclusive scan over 512 (1 per thread)
    int v = ncnt[t];
    sd[t] = v;
    __syncthreads();
    for (int off = 1; off < 512; off <<= 1) {
        int add = (t >= off) ? sd[t - off] : 0;
        __syncthreads();
        sd[t] += add;
        __syncthreads();
    }
    int ex = sd[t] - v;
    ncur[t] = ex;
    if (lo + t < hi) rowptr[lo + t] = r0 + ex;
    if (b == NB - 1 && t == 0) rowptr[N] = r0 + cntE;  // == E
    __syncthreads();
    bool fit = (cntE <= COLS);
    if (fit) {
        for (int i = t; i < cntE; i += 512) {
            unsigned p = pairs[r0 + i];
            int slot = atomicAdd(&ncur[p >> P_SH], 1);
            stg[slot] = p;
        }
        __syncthreads();
        for (int i = t; i < cntE; i += 512) {
            unsigned p = stg[i];
            int ldst = (int)(p >> P_SH);
            int src = (int)(p & PMASK);
            float dx = posS[ldst * 3 + 0] - pos[(size_t)src * 3 + 0];
            float dy = posS[ldst * 3 + 1] - pos[(size_t)src * 3 + 1];
            float dz = posS[ldst * 3 + 2] - pos[(size_t)src * 3 + 2];
            float d = sqrtf(fmaf(dx, dx, fmaf(dy, dy, dz * dz)));
            unsigned wq = (unsigned)fminf(fmaf(d, WSCALE, 0.5f), 8191.0f);
            cw[r0 + i] = (unsigned)src | (wq << CW_SH);
            atomicAdd(&wsum[ldst], d);
        }
    } else {
        // overflow fallback (practically unreachable)
        for (int i = t; i < cntE; i += 512) {
            unsigned p = pairs[r0 + i];
            int ldst = (int)(p >> P_SH);
            int src = (int)(p & PMASK);
            int slot = atomicAdd(&ncur[ldst], 1);
            float dx = posS[ldst * 3 + 0] - pos[(size_t)src * 3 + 0];
            float dy = posS[ldst * 3 + 1] - pos[(size_t)src * 3 + 1];
            float dz = posS[ldst * 3 + 2] - pos[(size_t)src * 3 + 2];
            float d = sqrtf(fmaf(dx, dx, fmaf(dy, dy, dz * dz)));
            unsigned wq = (unsigned)fminf(fmaf(d, WSCALE, 0.5f), 8191.0f);
            cw[r0 + slot] = (unsigned)src | (wq << CW_SH);
            atomicAdd(&wsum[ldst], d);
        }
    }
    __syncthreads();
    // epilogue: dinv + fused node_init -> zh1, 8-lane groups (low VGPR).
    int g = t >> 3, c = t & 7;          // 64 groups x 8 lanes
    for (int j = 0; j < BQ / 64; j++) {
        int nl = j * 64 + g;
        if (nl < nloc) {
            float p0 = posS[nl * 3 + 0];
            float p1 = posS[nl * 3 + 1];
            float p2 = posS[nl * 3 + 2];
            int k0 = 2 * c, k1 = 2 * c + 1;
            float h0 = fmaf(p0, sWi[0 * EM + k0],
                       fmaf(p1, sWi[1 * EM + k0],
                       fmaf(p2, sWi[2 * EM + k0], sbi[k0])));
            float h1 = fmaf(p0, sWi[0 * EM + k1],
                       fmaf(p1, sWi[1 * EM + k1],
                       fmaf(p2, sWi[2 * EM + k1], sbi[k1])));
            lx[g][k0] = sp(h0);
            lx[g][k1] = sp(h1);
            float di = rsqrtf(1.0f + wsum[nl]);
            int n = lo + nl;
            if (c == 0) dinv[n] = di;
            float ax = 0.0f, ay = 0.0f;
#pragma unroll
            for (int jj = 0; jj < EM; jj++) {
                float lj = lx[g][jj];
                ax = fmaf(lj, sW1[jj * EM + k0], ax);
                ay = fmaf(lj, sW1[jj * EM + k1], ay);
            }
            zh1[(size_t)n * 8 + c] =
                __float22half2_rn(make_float2(ax * di, ay * di));
        }
    }
}

// Kernel 6 (x2): fused GCN-mean layer on fp16 pre-scaled operand
// zh[s][c] = fp16(dinv[s]*x[s][c]). 8 lanes/node (lane = channel pair).
// Per edge per lane: one cached u32 cw load (broadcast across the group,
// line-reused across j -> plain loads, NOT nt; r15 showed nt re-fetches
// the broadcast line, +30MB) + one half2 z load; f32 accumulate.
// mode 1: zout = fp16((x@W)*di)  (pre-scaled layer-2 operand).
// mode 2: fused head: y = sp(x@P1+b1); out = (y@P2+b2)/sig.
__global__ __launch_bounds__(256) void gather_conv(
    const int* __restrict__ rowptr, const unsigned int* __restrict__ cw,
    const float* __restrict__ dinv, const __half2* __restrict__ zin,
    const float* __restrict__ bconv, const float* __restrict__ W,
    const float* __restrict__ P1, const float* __restrict__ b1,
    const float* __restrict__ P2, const float* __restrict__ b2,
    const float* __restrict__ sig,
    __half2* __restrict__ zout, float* __restrict__ out, int N, int mode)
{
    __shared__ float sW[EM * EM];
    __shared__ float sP2[EM * ND];
    __shared__ float sb1[EM];
    __shared__ float sb2[ND];
    __shared__ float lx[32][EM + 1];
    int t = threadIdx.x;
    if (mode == 1) {
        sW[t] = W[t];
    } else {
        sW[t] = P1[t];
        if (t < EM)      sb1[t] = b1[t];
        if (t < EM * ND) sP2[t] = P2[t];
        if (t < ND)      sb2[t] = b2[t];
    }
    int g = t >> 3, c = t & 7;          // 32 node groups, 8 lanes each
    int n = blockIdx.x * 32 + g;

    float xx = 0.0f, xy = 0.0f;
    float di = 1.0f;
    if (n < N) {
        int start = rowptr[n], end = rowptr[n + 1];
        di = dinv[n];
        float2 zv = __half22float2(zin[(size_t)n * 8 + c]);  // self loop
        float a0x = zv.x, a0y = zv.y;
        float a1x = 0.f, a1y = 0.f, a2x = 0.f, a2y = 0.f, a3x = 0.f, a3y = 0.f;
        int j = start;
        for (; j + 3 < end; j += 4) {
            unsigned p0 = cw[j],     p1 = cw[j + 1];
            unsigned p2 = cw[j + 2], p3 = cw[j + 3];
            float2 z0 = __half22float2(zin[(size_t)(p0 & CW_SRCM) * 8 + c]);
            float2 z1 = __half22float2(zin[(size_t)(p1 & CW_SRCM) * 8 + c]);
            float2 z2 = __half22float2(zin[(size_t)(p2 & CW_SRCM) * 8 + c]);
            float2 z3 = __half22float2(zin[(size_t)(p3 & CW_SRCM) * 8 + c]);
            float w0 = (float)(p0 >> CW_SH) * WINV;
            float w1 = (float)(p1 >> CW_SH) * WINV;
            float w2 = (float)(p2 >> CW_SH) * WINV;
            float w3 = (float)(p3 >> CW_SH) * WINV;
            a0x = fmaf(w0, z0.x, a0x); a0y = fmaf(w0, z0.y, a0y);
            a1x = fmaf(w1, z1.x, a1x); a1y = fmaf(w1, z1.y, a1y);
            a2x = fmaf(w2, z2.x, a2x); a2y = fmaf(w2, z2.y, a2y);
            a3x = fmaf(w3, z3.x, a3x); a3y = fmaf(w3, z3.y, a3y);
        }
        for (; j < end; j++) {
            unsigned p = cw[j];
            float2 zr = __half22float2(zin[(size_t)(p & CW_SRCM) * 8 + c]);
            float wv = (float)(p >> CW_SH) * WINV;
            a0x = fmaf(wv, zr.x, a0x); a0y = fmaf(wv, zr.y, a0y);
        }
        float accx = (a0x + a1x) + (a2x + a3x);
        float accy = (a0y + a1y) + (a2y + a3y);
        float rc = 1.0f / (float)(end - start + 1);
        xx = sp(fmaf(accx * di, rc, bconv[2 * c]));
        xy = sp(fmaf(accy * di, rc, bconv[2 * c + 1]));
    }
    __syncthreads();      // sW/lx ready
    lx[g][2 * c]     = xx;
    lx[g][2 * c + 1] = xy;
    __syncthreads();
    if (n < N) {
        if (mode == 1) {
            float ax = 0.0f, ay = 0.0f;
#pragma unroll
            for (int j = 0; j < EM; j++) {
                float lj = lx[g][j];
                ax = fmaf(lj, sW[j * EM + 2 * c], ax);
                ay = fmaf(lj, sW[j * EM + 2 * c + 1], ay);
            }
            zout[(size_t)n * 8 + c] =
                __float22half2_rn(make_float2(ax * di, ay * di));
        } else {
            // fused head: y = sp(x@P1+b1) over own row (wave-lockstep safe),
            // then out = (y@P2+b2)/sig.
            float ax = sb1[2 * c], ay = sb1[2 * c + 1];
#pragma unroll
            for (int j = 0; j < EM; j++) {
                float lj = lx[g][j];
                ax = fmaf(lj, sW[j * EM + 2 * c], ax);
                ay = fmaf(lj, sW[j * EM + 2 * c + 1], ay);
            }
            lx[g][2 * c]     = sp(ax);
            lx[g][2 * c + 1] = sp(ay);
            if (c < ND) {
                float o = sb2[c];
#pragma unroll
                for (int j = 0; j < EM; j++)
                    o = fmaf(lx[g][j], sP2[j * ND + c], o);
                out[(size_t)n * ND + c] = o / sig[n];
            }
        }
    }
}

extern "C" void kernel_launch(void* const* d_in, const int* in_sizes, int n_in,
                              void* d_out, int out_size, void* d_ws, size_t ws_size,
                              hipStream_t stream) {
    const float* pos    = (const float*)d_in[0];
    const float* sig    = (const float*)d_in[1];
    const int*   ei     = (const int*)d_in[2];
    const float* W_init = (const float*)d_in[4];
    const float* b_init = (const float*)d_in[5];
    const float* W_g1   = (const float*)d_in[6];
    const float* b_g1   = (const float*)d_in[7];
    const float* W_g2   = (const float*)d_in[8];
    const float* b_g2   = (const float*)d_in[9];
    const float* W_p1   = (const float*)d_in[10];
    const float* b_p1   = (const float*)d_in[11];
    const float* W_p2   = (const float*)d_in[12];
    const float* b_p2   = (const float*)d_in[13];
    float* out = (float*)d_out;

    int N = in_sizes[0] / ND;
    int E = in_sizes[2] / 2;
    size_t Ns = (size_t)N, Es = (size_t)E;
    int NB = (N + BQ - 1) >> BQ_SH;   // <= MAXB for N <= 524288

    // Workspace layout (4B elements):
    // rowptr[N+1] | bcnt[1024] | gbase[1024] | gcur[1024] | dinv[N]
    //   | cw[E] (u32) | pairs[E] (u32) | zh1[8N] (half2)
    // zh2 (8N half2 = 16MB) aliases pairs (32MB, dead after bucket_csr_init).
    int* rowptr = (int*)d_ws;
    int* bcnt   = rowptr + (Ns + 1);
    int* gbase  = bcnt + 1024;
    int* gcur   = gbase + 1024;
    float* dinv = (float*)(gcur + 1024);
    unsigned int* cw = (unsigned int*)(dinv + Ns);
    unsigned int* pairs = cw + Es;
    __half2* zh2 = (__half2*)pairs;
    __half2* zh1 = (__half2*)(pairs + Es);

    int nbG2 = (N + 31) / 32;           // gather_conv: 32 nodes/block
    int nbBin = (E + CHK - 1) / CHK;

    bucket_zero<<<1, 1024, 0, stream>>>(bcnt);
    bucket_count<<<1024, 256, 0, stream>>>(ei, bcnt, E, NB);
    bucket_scan<<<1, 1024, 0, stream>>>(bcnt, gbase, gcur, NB);
    edge_bin<<<nbBin, 512, 0, stream>>>(ei, gcur, pairs, E);
    bucket_csr_init<<<NB, 512, 0, stream>>>(pairs, gbase, bcnt, pos,
        W_init, b_init, W_g1, rowptr, cw, dinv, zh1, N, NB);
    gather_conv<<<nbG2, 256, 0, stream>>>(rowptr, cw, dinv, zh1, b_g1, W_g2,
        W_p1, b_p1, W_p2, b_p2, sig, zh2, out, N, 1);
    gather_conv<<<nbG2, 256, 0, stream>>>(rowptr, cw, dinv, zh2, b_g2, W_g2,
        W_p1, b_p1, W_p2, b_p2, sig, zh2, out, N, 2);
}